// Round 2
// 216.726 us; speedup vs baseline: 1.0363x; 1.0363x over previous
//
#include <hip/hip_runtime.h>

typedef unsigned short u16;
typedef short bf16x8 __attribute__((ext_vector_type(8)));
typedef float f32x4 __attribute__((ext_vector_type(4)));
typedef float f32x16 __attribute__((ext_vector_type(16)));

namespace {

constexpr int kB = 2, kS = 2048, kD = 1024, kH = 16, kDh = 64;
constexpr float kC2 = 0.125f * 1.44269504088896341f;  // score scale * log2(e)

__device__ inline u16 f32_bf16(float f) {
    unsigned u = __float_as_uint(f);
    u += 0x7FFFu + ((u >> 16) & 1u);        // RNE
    return (u16)(u >> 16);
}

__device__ inline float fast_exp2(float x) {     // raw v_exp_f32 (1 instr)
    float r;
    asm("v_exp_f32 %0, %1" : "=v"(r) : "v"(x));
    return r;
}

__device__ inline unsigned cvtpk(float a, float b) {  // {lo=bf16(a), hi=bf16(b)}
    unsigned r;
    asm("v_cvt_pk_bf16_f32 %0, %1, %2" : "=v"(r) : "v"(a), "v"(b));
    return r;
}

// v_permlane32_swap_b32 a, b : swaps a's upper 32 lanes with b's lower 32 lanes.
// After: a = {a.lo32, b.lo32(lifted)}, b = {a.hi32(lowered), b.hi32}.
__device__ inline void plswap(unsigned& a, unsigned& b) {
    asm("v_permlane32_swap_b32 %0, %1" : "+v"(a), "+v"(b));
}

__device__ inline void gl_lds16(const void* g, void* l) {
    __builtin_amdgcn_global_load_lds(
        (const __attribute__((address_space(1))) void*)g,
        (__attribute__((address_space(3))) void*)l, 16, 0, 0);
}

__device__ inline int swz8(int l) {   // GEMM staging swizzle (u16 units)
    return ((l & 3) ^ ((l >> 2) & 3) ^ ((l >> 4) & 3)) * 8;
}

// ------- fused prep: fp32->bf16 convert (y<3) + weight transpose (y>=3) ----
// Wq (z==0) pre-scaled by kC2 so attention scores arrive exp2-ready.
__global__ __launch_bounds__(256) void prep(
    const float* __restrict__ s0, const float* __restrict__ s1,
    const float* __restrict__ s2,
    u16* __restrict__ d0, u16* __restrict__ d1, u16* __restrict__ d2,
    const float* __restrict__ W0, const float* __restrict__ W1,
    const float* __restrict__ W2, const float* __restrict__ W3,
    u16* __restrict__ T0, u16* __restrict__ T1,
    u16* __restrict__ T2, u16* __restrict__ T3)
{
    const int y = blockIdx.y;
    if (y < 3) {
        const float* src = y == 0 ? s0 : (y == 1 ? s1 : s2);
        u16* dst = y == 0 ? d0 : (y == 1 ? d1 : d2);
        const int i = blockIdx.x * 256 + threadIdx.x;
        const float4* s4 = (const float4*)src;
        float4 a = s4[2 * i], b = s4[2 * i + 1];
        uint4 o;
        o.x = (unsigned)f32_bf16(a.x) | ((unsigned)f32_bf16(a.y) << 16);
        o.y = (unsigned)f32_bf16(a.z) | ((unsigned)f32_bf16(a.w) << 16);
        o.z = (unsigned)f32_bf16(b.x) | ((unsigned)f32_bf16(b.y) << 16);
        o.w = (unsigned)f32_bf16(b.z) | ((unsigned)f32_bf16(b.w) << 16);
        ((uint4*)dst)[i] = o;
        return;
    }
    if (blockIdx.x >= 256) return;
    const int z = y - 3;
    const float* W = z == 0 ? W0 : (z == 1 ? W1 : (z == 2 ? W2 : W3));
    u16* Wt = z == 0 ? T0 : (z == 1 ? T1 : (z == 2 ? T2 : T3));
    const float sc = (z == 0) ? kC2 : 1.0f;

    __shared__ __attribute__((aligned(16))) u16 T[64][65];  // [k][n]
    const int t = threadIdx.x;
    const int n0 = (blockIdx.x & 15) * 64, k0 = (blockIdx.x >> 4) * 64;
    const int r = t >> 4, c4 = (t & 15) * 4;
#pragma unroll
    for (int it = 0; it < 4; ++it) {
        const int rr = r + 16 * it;
        float4 v = *(const float4*)(W + (size_t)(k0 + rr) * kD + n0 + c4);
        T[rr][c4 + 0] = f32_bf16(v.x * sc);
        T[rr][c4 + 1] = f32_bf16(v.y * sc);
        T[rr][c4 + 2] = f32_bf16(v.z * sc);
        T[rr][c4 + 3] = f32_bf16(v.w * sc);
    }
    __syncthreads();
#pragma unroll
    for (int it = 0; it < 4; ++it) {
        const int nn = r + 16 * it;
        uint2 pk;
        pk.x = (unsigned)T[c4 + 0][nn] | ((unsigned)T[c4 + 1][nn] << 16);
        pk.y = (unsigned)T[c4 + 2][nn] | ((unsigned)T[c4 + 3][nn] << 16);
        *(uint2*)(Wt + (size_t)(n0 + nn) * kD + k0 + c4) = pk;
    }
}

// --------- V transpose (bf16): V[b,s,1024] -> Vt[bh=32][dh=64][s=2048] -----
__global__ __launch_bounds__(256) void vtrans(
    const u16* __restrict__ V, u16* __restrict__ Vt)
{
    __shared__ __attribute__((aligned(16))) u16 T[64][65];  // [d][s]
    const int t = threadIdx.x;
    const int s0 = blockIdx.x * 64;
    const int bh = blockIdx.y, b = bh >> 4, h = bh & 15;
    const int rr = t >> 3, c0 = (t & 7) * 8;
    union { u16 u[8]; uint4 v4; } buf;
#pragma unroll
    for (int p = 0; p < 2; ++p) {
        const int s = rr + 32 * p;
        buf.v4 = *(const uint4*)(V + (size_t)(b * kS + s0 + s) * kD + h * kDh + c0);
#pragma unroll
        for (int i = 0; i < 8; ++i) T[c0 + i][s] = buf.u[i];
    }
    __syncthreads();
#pragma unroll
    for (int p = 0; p < 2; ++p) {
        const int d = rr + 32 * p;
#pragma unroll
        for (int i = 0; i < 8; ++i) buf.u[i] = T[d][c0 + i];
        *(uint4*)(Vt + (size_t)(bh * kDh + d) * kS + s0 + c0) = buf.v4;
    }
}

// ---- m97-style bf16 MFMA GEMM: C[M,N] = A[M,K] @ Wt[N,K]^T, 128x128 tile --
template <bool F32OUT>
__device__ inline void gemm128_body(
    const u16* __restrict__ A, const u16* __restrict__ Wt,
    void* __restrict__ Cout, int M, int N, int K, int bx, int by)
{
    __shared__ __attribute__((aligned(16))) u16 As[128 * 32];
    __shared__ __attribute__((aligned(16))) u16 Bs[128 * 32];
    const int t = threadIdx.x, w = t >> 6, l = t & 63;
    const int quad = l >> 4, c = l & 15;
    const int wm = w >> 1, wn = w & 1;
    const int m0 = by * 128, n0 = bx * 128;
    const int lr = l >> 2, lc = swz8(l);
    const int xc = ((quad ^ (c & 3) ^ ((c >> 2) & 3))) * 8;

    const u16* ga0 = A  + (size_t)(m0 + w * 32 + lr) * K + lc;
    const u16* ga1 = A  + (size_t)(m0 + w * 32 + 16 + lr) * K + lc;
    const u16* gb0 = Wt + (size_t)(n0 + w * 32 + lr) * K + lc;
    const u16* gb1 = Wt + (size_t)(n0 + w * 32 + 16 + lr) * K + lc;
    u16* la0 = &As[(w * 32) * 32];
    u16* la1 = &As[(w * 32 + 16) * 32];
    u16* lb0 = &Bs[(w * 32) * 32];
    u16* lb1 = &Bs[(w * 32 + 16) * 32];

    f32x4 acc[4][4];
#pragma unroll
    for (int mi = 0; mi < 4; ++mi)
#pragma unroll
        for (int nj = 0; nj < 4; ++nj) acc[mi][nj] = 0;

    for (int k0 = 0; k0 < K; k0 += 32) {
        gl_lds16(ga0 + k0, la0);
        gl_lds16(ga1 + k0, la1);
        gl_lds16(gb0 + k0, lb0);
        gl_lds16(gb1 + k0, lb1);
        __syncthreads();
        bf16x8 af[4], bf[4];
#pragma unroll
        for (int mi = 0; mi < 4; ++mi)
            af[mi] = *(const bf16x8*)&As[(wm * 64 + mi * 16 + c) * 32 + xc];
#pragma unroll
        for (int nj = 0; nj < 4; ++nj)
            bf[nj] = *(const bf16x8*)&Bs[(wn * 64 + nj * 16 + c) * 32 + xc];
#pragma unroll
        for (int mi = 0; mi < 4; ++mi)
#pragma unroll
            for (int nj = 0; nj < 4; ++nj)
                acc[mi][nj] = __builtin_amdgcn_mfma_f32_16x16x32_bf16(
                    af[mi], bf[nj], acc[mi][nj], 0, 0, 0);
        __syncthreads();
    }

#pragma unroll
    for (int mi = 0; mi < 4; ++mi)
#pragma unroll
        for (int nj = 0; nj < 4; ++nj)
#pragma unroll
            for (int r = 0; r < 4; ++r) {
                const size_t row = m0 + wm * 64 + mi * 16 + quad * 4 + r;
                const size_t col = n0 + wn * 64 + nj * 16 + c;
                if (F32OUT)
                    ((float*)Cout)[row * N + col] = acc[mi][nj][r];
                else
                    ((u16*)Cout)[row * N + col] = f32_bf16(acc[mi][nj][r]);
            }
}

__global__ __launch_bounds__(256) void gemm_qkv(
    const u16* __restrict__ A0, const u16* __restrict__ A1,
    const u16* __restrict__ A2,
    const u16* __restrict__ W0, const u16* __restrict__ W1,
    const u16* __restrict__ W2,
    u16* __restrict__ C0, u16* __restrict__ C1, u16* __restrict__ C2)
{
    const int z = blockIdx.z;
    const u16* A  = z == 0 ? A0 : (z == 1 ? A1 : A2);
    const u16* Wt = z == 0 ? W0 : (z == 1 ? W1 : W2);
    u16* C = z == 0 ? C0 : (z == 1 ? C1 : C2);
    gemm128_body<false>(A, Wt, C, kB * kS, kD, kD, blockIdx.x, blockIdx.y);
}

// ---- 64x128-tile GEMM for the output projection (512 blocks = 2/CU) -------
__global__ __launch_bounds__(256) void gemm_out(
    const u16* __restrict__ A, const u16* __restrict__ Wt,
    float* __restrict__ C)
{
    __shared__ __attribute__((aligned(16))) u16 As[64 * 32];
    __shared__ __attribute__((aligned(16))) u16 Bs[128 * 32];
    const int N = kD, K = kD;
    const int t = threadIdx.x, w = t >> 6, l = t & 63;
    const int quad = l >> 4, c = l & 15;
    const int wm = w >> 1, wn = w & 1;
    const int m0 = blockIdx.y * 64, n0 = blockIdx.x * 128;
    const int lr = l >> 2, lc = swz8(l);
    const int xc = ((quad ^ (c & 3) ^ ((c >> 2) & 3))) * 8;

    const u16* ga  = A  + (size_t)(m0 + w * 16 + lr) * K + lc;
    const u16* gb0 = Wt + (size_t)(n0 + w * 16 + lr) * K + lc;
    const u16* gb1 = Wt + (size_t)(n0 + 64 + w * 16 + lr) * K + lc;
    u16* la  = &As[(w * 16) * 32];
    u16* lb0 = &Bs[(w * 16) * 32];
    u16* lb1 = &Bs[(64 + w * 16) * 32];

    f32x4 acc[2][4];
#pragma unroll
    for (int mi = 0; mi < 2; ++mi)
#pragma unroll
        for (int nj = 0; nj < 4; ++nj) acc[mi][nj] = 0;

    for (int k0 = 0; k0 < K; k0 += 32) {
        gl_lds16(ga + k0, la);
        gl_lds16(gb0 + k0, lb0);
        gl_lds16(gb1 + k0, lb1);
        __syncthreads();
        bf16x8 af[2], bf[4];
#pragma unroll
        for (int mi = 0; mi < 2; ++mi)
            af[mi] = *(const bf16x8*)&As[(wm * 32 + mi * 16 + c) * 32 + xc];
#pragma unroll
        for (int nj = 0; nj < 4; ++nj)
            bf[nj] = *(const bf16x8*)&Bs[(wn * 64 + nj * 16 + c) * 32 + xc];
#pragma unroll
        for (int mi = 0; mi < 2; ++mi)
#pragma unroll
            for (int nj = 0; nj < 4; ++nj)
                acc[mi][nj] = __builtin_amdgcn_mfma_f32_16x16x32_bf16(
                    af[mi], bf[nj], acc[mi][nj], 0, 0, 0);
        __syncthreads();
    }

#pragma unroll
    for (int mi = 0; mi < 2; ++mi)
#pragma unroll
        for (int nj = 0; nj < 4; ++nj)
#pragma unroll
            for (int r = 0; r < 4; ++r) {
                const size_t row = m0 + wm * 32 + mi * 16 + quad * 4 + r;
                const size_t col = n0 + wn * 64 + nj * 16 + c;
                C[row * N + col] = acc[mi][nj][r];
            }
}

// ------------- MFMA flash attention: swapped-QK, in-register softmax -------
//  * QK^T computed as mfma(K, Q^T) -> S^T[key][q] with q = lane&31: the
//    softmax reduction axis (key) is spread across REGS, so the denominator
//    is a lane-local f32 accumulation (ones-MFMA deleted: -20% MFMA issue).
//  * P never touches LDS: per 16-key slice, 4x v_cvt_pk_bf16_f32 + 2x
//    v_permlane32_swap_b32 assemble the PV B-fragment P^T[k][q] in registers.
//  * PV computes O^T = V^T x P^T; Vt LDS reads identical to the old layout.
//  * Qs/Ps LDS dropped. LDS: 64KB -> 32KB/block.
//  * Epilogue: each wave transposes its O^T tile (32q x 64d = 2048 u16)
//    through its OWN dead K/V double-buffer (KsA/KsB/VtA/VtB, 4096 u16 each
//    -- full tile fits, no cross-wave overlap), XOR-swizzled 16B slots, then
//    4x uint4 coalesced global stores. [R1 bug: waves at stride 1024 inside
//    KsA overlapped and raced -> absmax 0.17. Fixed: one buffer per wave.]
__global__ __launch_bounds__(256) void attn(
    const u16* __restrict__ Q, const u16* __restrict__ K,
    const u16* __restrict__ Vt, u16* __restrict__ AO)
{
    __shared__ __attribute__((aligned(16))) u16 KsA[64 * 64];      // [key][dh]
    __shared__ __attribute__((aligned(16))) u16 KsB[64 * 64];
    __shared__ __attribute__((aligned(16))) u16 VtA[64 * 64];      // [d][key]
    __shared__ __attribute__((aligned(16))) u16 VtB[64 * 64];

    const int t = threadIdx.x, w = t >> 6, l = t & 63;
    const int half = l >> 5, m = l & 31;      // fragment coords (m = q or d row)
    const int q0 = blockIdx.x * 128;
    const int bh = blockIdx.y, b = bh >> 4, h = bh & 15;
    const int sr = l >> 3;                    // staging row within 8-row group
    const int sc = (l & 7) ^ sr;              // staging global chunk (swizzled)

    const size_t kbase = (size_t)(b * kS) * kD + h * kDh;
    const size_t vbase = (size_t)bh * kDh * kS;

    // stage one K/V tile (wave w covers rows w*16..w*16+15 of the 64)
    auto stage = [&](int kt, u16* KsP, u16* VtP) {
#pragma unroll
        for (int i = 0; i < 2; ++i) {
            const int R0 = w * 16 + i * 8;
            gl_lds16(K + kbase + (size_t)(kt * 64 + R0 + sr) * kD + sc * 8,
                     &KsP[R0 * 64]);
            gl_lds16(Vt + vbase + (size_t)(R0 + sr) * kS + kt * 64 + sc * 8,
                     &VtP[R0 * 64]);
        }
    };

    stage(0, KsA, VtA);

    // Q fragments straight from global: lane (q=m, half) holds
    // Q[q0+w*32+m][16*ch + 8*half + 0..7] -- the B-operand (Q^T) layout.
    bf16x8 qf[4];
    {
        const u16* qp = Q + (size_t)(b * kS + q0 + w * 32 + m) * kD
                        + h * kDh + half * 8;
#pragma unroll
        for (int ch = 0; ch < 4; ++ch)
            qf[ch] = *(const bf16x8*)(qp + ch * 16);
    }

    f32x16 o0 = 0, o1 = 0;   // O^T rows d=0..31 (o0), 32..63 (o1); col q=m
    f32x4 lsum = 0;          // lane-local partial softmax denominator

    __syncthreads();

    // compute one 64-key tile from the given buffers
    auto compute = [&](const u16* KsP, const u16* VtP) {
        f32x16 s0 = 0, s1 = 0;   // S^T[key][q]: s0 keys 0..31, s1 keys 32..63
        __builtin_amdgcn_s_setprio(1);
#pragma unroll
        for (int ch = 0; ch < 4; ++ch) {
            const int xo = ((2 * ch + half) ^ (m & 7)) * 8;
            const bf16x8 kf0 = *(const bf16x8*)&KsP[(m) * 64 + xo];
            const bf16x8 kf1 = *(const bf16x8*)&KsP[(32 + m) * 64 + xo];
            // swapped operands: A = K-tile rows (keys), B = Q^T -> D[key][q]
            s0 = __builtin_amdgcn_mfma_f32_32x32x16_bf16(kf0, qf[ch], s0, 0, 0, 0);
            s1 = __builtin_amdgcn_mfma_f32_32x32x16_bf16(kf1, qf[ch], s1, 0, 0, 0);
        }
        __builtin_amdgcn_s_setprio(0);
        // exp2 in place + lane-local denominator accumulation
#pragma unroll
        for (int r = 0; r < 16; ++r) {
            s0[r] = fast_exp2(s0[r]);
            s1[r] = fast_exp2(s1[r]);
        }
#pragma unroll
        for (int r = 0; r < 16; r += 4) {
            lsum += (f32x4){s0[r], s0[r + 1], s0[r + 2], s0[r + 3]};
            lsum += (f32x4){s1[r], s1[r + 1], s1[r + 2], s1[r + 3]};
        }
        // per 16-key slice: build P^T B-fragment in regs, fused with PV MFMA
        __builtin_amdgcn_s_setprio(1);
#pragma unroll
        for (int ts = 0; ts < 4; ++ts) {
            const int rb = (ts & 1) * 8;
            unsigned c0, c1, c2, c3;
            if (ts < 2) {
                c0 = cvtpk(s0[rb + 0], s0[rb + 1]);
                c1 = cvtpk(s0[rb + 2], s0[rb + 3]);
                c2 = cvtpk(s0[rb + 4], s0[rb + 5]);
                c3 = cvtpk(s0[rb + 6], s0[rb + 7]);
            } else {
                c0 = cvtpk(s1[rb + 0], s1[rb + 1]);
                c1 = cvtpk(s1[rb + 2], s1[rb + 3]);
                c2 = cvtpk(s1[rb + 4], s1[rb + 5]);
                c3 = cvtpk(s1[rb + 6], s1[rb + 7]);
            }
            plswap(c0, c2);   // c0 -> frag word0, c2 -> frag word2
            plswap(c1, c3);   // c1 -> frag word1, c3 -> frag word3
            union { unsigned u[4]; bf16x8 v; } pb;
            pb.u[0] = c0; pb.u[1] = c1; pb.u[2] = c2; pb.u[3] = c3;
            const int xo = ((2 * ts + half) ^ (m & 7)) * 8;
            const bf16x8 vf0 = *(const bf16x8*)&VtP[(m) * 64 + xo];
            const bf16x8 vf1 = *(const bf16x8*)&VtP[(32 + m) * 64 + xo];
            // O^T = V^T x P^T : A = Vt rows (d), B = P^T -> D[d][q]
            o0 = __builtin_amdgcn_mfma_f32_32x32x16_bf16(vf0, pb.v, o0, 0, 0, 0);
            o1 = __builtin_amdgcn_mfma_f32_32x32x16_bf16(vf1, pb.v, o1, 0, 0, 0);
        }
        __builtin_amdgcn_s_setprio(0);
    };

    constexpr int NT = kS / 64;   // 32, even
#pragma unroll 1
    for (int kt = 0; kt < NT; kt += 2) {
        if (kt + 1 < NT) stage(kt + 1, KsB, VtB);   // prefetch into B
        compute(KsA, VtA);
        __syncthreads();   // everyone done reading A; B landed during compute
        if (kt + 2 < NT) stage(kt + 2, KsA, VtA);   // prefetch into A
        compute(KsB, VtB);
        __syncthreads();   // everyone done reading B; A landed during compute
    }

    // ---- epilogue: combine half-denominators, normalize, transpose, store
    float lt = lsum[0] + lsum[1] + lsum[2] + lsum[3];
    lt += __shfl_xor(lt, 32, 64);     // other half of this q's keys
    const float inv = 1.0f / lt;

    // wave-private 32q x 64d bf16 tile in the wave's OWN dead buffer
    u16* ob = w == 0 ? KsA : (w == 1 ? KsB : (w == 2 ? VtA : VtB));
#pragma unroll
    for (int r = 0; r < 4; ++r) {
        // o0 regs 4r..4r+3 -> d = 8r + 4*half + 0..3 (chunk r, sub-half)
        uint2 p0, p1;
        p0.x = cvtpk(o0[4 * r + 0] * inv, o0[4 * r + 1] * inv);
        p0.y = cvtpk(o0[4 * r + 2] * inv, o0[4 * r + 3] * inv);
        p1.x = cvtpk(o1[4 * r + 0] * inv, o1[4 * r + 1] * inv);
        p1.y = cvtpk(o1[4 * r + 2] * inv, o1[4 * r + 3] * inv);
        *(uint2*)&ob[m * 64 + ((r ^ (m & 7)) << 3) + 4 * half] = p0;
        *(uint2*)&ob[m * 64 + (((4 + r) ^ (m & 7)) << 3) + 4 * half] = p1;
    }
    // same-wave LDS readback (compiler inserts the lgkmcnt dependence wait)
    const size_t obase = (size_t)(b * kS + q0 + w * 32) * kD + h * kDh;
#pragma unroll
    for (int i = 0; i < 4; ++i) {
        const int q = l >> 1;             // 0..31
        const int tt = (l & 1) + i * 2;   // d-chunk 0..7
        uint4 dd = *(const uint4*)&ob[q * 64 + ((tt ^ (q & 7)) << 3)];
        *(uint4*)(AO + obase + (size_t)q * kD + tt * 8) = dd;
    }
}

}  // namespace

extern "C" void kernel_launch(void* const* d_in, const int* in_sizes, int n_in,
                              void* d_out, int out_size, void* d_ws, size_t ws_size,
                              hipStream_t stream)
{
    const float* q_in = (const float*)d_in[0];
    const float* k_in = (const float*)d_in[1];
    const float* v_in = (const float*)d_in[2];
    const float* Wq   = (const float*)d_in[3];
    const float* Wk   = (const float*)d_in[4];
    const float* Wv   = (const float*)d_in[5];
    const float* Wo   = (const float*)d_in[6];

    u16* ws = (u16*)d_ws;
    const size_t M1 = 1u << 20;
    u16* xq  = ws;             // later reused as Vt_g (dead after QKV GEMMs)
    u16* xk  = ws + 4 * M1;
    u16* xv  = ws + 8 * M1;
    u16* Wtq = ws + 12 * M1;
    u16* Wtk = ws + 13 * M1;
    u16* Wtv = ws + 14 * M1;
    u16* Wto = ws + 15 * M1;
    u16* Qp  = ws + 16 * M1;
    u16* Kp  = ws + 20 * M1;
    u16* Vp  = ws + 24 * M1;
    u16* AO  = ws + 28 * M1;
    u16* Vtg = xq;

    hipLaunchKernelGGL(prep, dim3(2048, 7), dim3(256), 0, stream,
                       q_in, k_in, v_in, xq, xk, xv,
                       Wq, Wk, Wv, Wo, Wtq, Wtk, Wtv, Wto);

    hipLaunchKernelGGL(gemm_qkv, dim3(8, 32, 3), dim3(256), 0, stream,
                       xq, xk, xv, Wtq, Wtk, Wtv, Qp, Kp, Vp);

    hipLaunchKernelGGL(vtrans, dim3(32, 32), dim3(256), 0, stream, Vp, Vtg);

    hipLaunchKernelGGL(attn, dim3(16, 32), dim3(256), 0, stream, Qp, Kp, Vtg, AO);

    hipLaunchKernelGGL(gemm_out, dim3(8, 64), dim3(256), 0, stream,
                       AO, Wto, (float*)d_out);
}